// Round 11
// baseline (353.157 us; speedup 1.0000x reference)
//
#include <hip/hip_runtime.h>
#include <hip/hip_bf16.h>
#include <hip/hip_fp16.h>
#include <math.h>

#define NN 50000
#define DD 64
#define MM 3
#define EE 100000
#define LL 4
#define HH 8
#define FHH 128
#define HD 512
#define NROWS (NN*MM)
#define LRELU_ALPHA 0.01f

#define WSUM_BINS 256
#define WSUM_SZ (MM*WSUM_BINS)
#define BINS (MM*NN)               /* 150,000 */
#define NBLK ((BINS + 1023)/1024)  /* 147 */
#define GT_TILE 224

/* prep_kernel block ranges */
#define FCVT_B 3125                /* NN*DD/4/256 */
#define CW1_B  64                  /* 16384 float4 / 256 */
#define UGEN_B 3
#define HISTG  392                 /* (EE+255)/256 */
#define HIST_B (HISTG*MM)
#define PREP_B (FCVT_B + CW1_B + UGEN_B + HIST_B + 1)

/* mid_kernel block ranges */
#define GT_B   (224*MM)            /* ceil(NN/GT_TILE)*MM = 672 */
#define MID_B  (GT_B + NBLK)

/* scat_kernel block ranges */
#define SCAT_B (HISTG*MM)          /* 1176 */
#define SEGC_B ((BINS + 255)/256)  /* 587 */
#define SCT_B  (SCAT_B + SEGC_B)

/* workspace layout (float offsets), all 16B aligned */
#define OFF_ZB    0                          /* bf16[NROWS*512] = 38.4M floats */
#define OFF_WSUM  (NROWS*HD/2)               /* 38,400,000 */
#define OFF_BETA  (OFF_WSUM + WSUM_SZ)
#define OFF_W1BF  (OFF_BETA + 16)
#define OFF_WU    (OFF_W1BF + 32768)         /* 3*32*64 = 6144 floats */
#define OFF_FRS   (OFF_WU + 6144)            /* 3*32*8 u32 = 768 */
#define OFF_GT    (OFF_FRS + 768)            /* f16[3*50000*32] = 2.4M floats used */
#define OFF_INTS  (OFF_GT + MM*NN*32)
#define IOFF_CNT    0
#define IOFF_CURSOR (IOFF_CNT + BINS)
#define IOFF_PART   (IOFF_CURSOR + BINS)
#define IOFF_BSUM   (IOFF_PART + BINS)
#define IOFF_BTOP   (IOFF_BSUM + 256)
#define IOFF_SEG8   (IOFF_BTOP + 256)        /* int[8*BINS] = 1.2M ints */
#define IOFF_REC    (IOFF_SEG8 + 8*BINS)     /* int4[MM*EE] = 1.2M ints */
#define INTS_END    (IOFF_REC + 4*MM*EE)
#define OFF_F16   (OFF_INTS + INTS_END)      /* f16[NN*DD] = 1.6M floats */

typedef short v8s __attribute__((ext_vector_type(8)));
typedef float v4f __attribute__((ext_vector_type(4)));

__device__ __forceinline__ float elu_f(float x) {
    return x > 0.f ? x : (__expf(x) - 1.f);
}

__device__ __forceinline__ float tanh_fast(float x) {
    float e = __expf(2.f * x);
    return 1.f - 2.f / (e + 1.f);
}

__device__ __forceinline__ unsigned int pk_bf16x2(float x, float y) {
    float2 f2; f2.x = x; f2.y = y;
    __hip_bfloat162 h = __float22bfloat162_rn(f2);
    union { __hip_bfloat162 h; unsigned int u; } cv;
    cv.h = h;
    return cv.u;
}

__device__ __forceinline__ unsigned int pk_h2(float x, float y) {
    __half2 h = __floats2half2_rn(x, y);
    union { __half2 h; unsigned int u; } cv;
    cv.h = h;
    return cv.u;
}

__device__ __forceinline__ float bf_lo(unsigned int u) {
    union { unsigned int x; float f; } c; c.x = u << 16; return c.f;
}
__device__ __forceinline__ float bf_hi(unsigned int u) {
    union { unsigned int x; float f; } c; c.x = u & 0xffff0000u; return c.f;
}

__device__ __forceinline__ __half2 u2h(unsigned int u) {
    union { unsigned int x; __half2 h; } c; c.x = u; return c.h;
}
__device__ __forceinline__ unsigned int h2u(__half2 h) {
    union { __half2 h; unsigned int x; } c; c.h = h; return c.x;
}

/* v_pk_fma_f16: d = s0*s1 + s2 (packed) */
__device__ __forceinline__ unsigned int pk_fma(unsigned int x, unsigned int c, unsigned int a) {
    unsigned int d;
    asm("v_pk_fma_f16 %0, %1, %2, %3"
        : "=v"(d) : "v"(x), "v"(c), "v"(a));
    return d;
}
/* same, src0 halves swapped (free via op_sel) */
__device__ __forceinline__ unsigned int pk_fma_swap0(unsigned int x, unsigned int c, unsigned int a) {
    unsigned int d;
    asm("v_pk_fma_f16 %0, %1, %2, %3 op_sel:[1,0,0] op_sel_hi:[0,1,1]"
        : "=v"(d) : "v"(x), "v"(c), "v"(a));
    return d;
}
/* same, src0 LOW half broadcast to both lanes */
__device__ __forceinline__ unsigned int pk_fma_bcast0(unsigned int x, unsigned int c, unsigned int a) {
    unsigned int d;
    asm("v_pk_fma_f16 %0, %1, %2, %3 op_sel:[0,0,0] op_sel_hi:[0,1,1]"
        : "=v"(d) : "v"(x), "v"(c), "v"(a));
    return d;
}
/* same, src0 HIGH half broadcast to both lanes */
__device__ __forceinline__ unsigned int pk_fma_bcast0hi(unsigned int x, unsigned int c, unsigned int a) {
    unsigned int d;
    asm("v_pk_fma_f16 %0, %1, %2, %3 op_sel:[1,0,0] op_sel_hi:[1,1,1]"
        : "=v"(d) : "v"(x), "v"(c), "v"(a));
    return d;
}

// compute frs chain for module m into LDS (threads 0..31)
__device__ __forceinline__ void build_frs(
    float frs[LL][DD/2][2], const float* r_vec, const int* etypes, int m, int t)
{
    if (t < DD/2) {
        float cr = 1.f, ci = 0.f;
        frs[LL-1][t][0] = 1.f; frs[LL-1][t][1] = 0.f;
        for (int i = LL-2; i >= 0; --i) {
            int et = etypes[m*(LL-1) + i];
            float rr = r_vec[((et>>1)*(DD/2) + t)*2 + 0];
            float ri = r_vec[((et>>1)*(DD/2) + t)*2 + 1];
            float inv = rsqrtf(rr*rr + ri*ri);
            rr *= inv; ri *= inv;
            if (et & 1) ri = -ri;
            float nr = cr*rr - ci*ri;
            float ni = cr*ri + ci*rr;
            cr = nr; ci = ni;
            frs[i][t][0] = cr; frs[i][t][1] = ci;
        }
    }
}

// ---------- merged prep: fcvt | cvt_w1 | ugen | hist | wsum-zero ----------
__global__ __launch_bounds__(256) void prep_kernel(
    const float* __restrict__ features, ushort* __restrict__ f16,
    const float* __restrict__ w1, ushort* __restrict__ w1bf,
    const float* __restrict__ r_vec, const int* __restrict__ etypes,
    const float* __restrict__ attn1_w, const float* __restrict__ attn2,
    float* __restrict__ Wu, unsigned int* __restrict__ frs_h,
    const int* __restrict__ inst, int* __restrict__ cnt,
    float* __restrict__ wsum)
{
    const int b = blockIdx.x;
    const int t = threadIdx.x;
    if (b < FCVT_B) {
        int i = b*256 + t;
        float4 v = ((const float4*)features)[i];
        ((uint2*)f16)[i] = make_uint2(pk_h2(v.x, v.y), pk_h2(v.z, v.w));
    } else if (b < FCVT_B + CW1_B) {
        int i = (b - FCVT_B)*256 + t;
        float4 v = ((const float4*)w1)[i];
        uint2 p; p.x = pk_bf16x2(v.x, v.y); p.y = pk_bf16x2(v.z, v.w);
        ((uint2*)w1bf)[i] = p;
    } else if (b < FCVT_B + CW1_B + UGEN_B) {
        const int m = b - (FCVT_B + CW1_B);
        __shared__ float frs[LL][DD/2][2];
        build_frs(frs, r_vec, etypes, m, t);
        __syncthreads();
        if (t < 32) {
            // packed half2 rotation consts, 0.25 folded:
            // [rr0, ii0, rr1, ii1], [rr2, ii2, rr3, ii3]
            unsigned int vals[8];
            #pragma unroll
            for (int l = 0; l < LL; ++l) {
                float fr = 0.25f * frs[l][t][0];
                float fi = 0.25f * frs[l][t][1];
                vals[2*l+0] = pk_h2(fr, fr);
                vals[2*l+1] = pk_h2(-fi, fi);
            }
            uint4* dst = (uint4*)frs_h + (m*32 + t)*2;
            dst[0] = make_uint4(vals[0], vals[1], vals[2], vals[3]);
            dst[1] = make_uint4(vals[4], vals[5], vals[6], vals[7]);
        }
        for (int idx = t; idx < 32*64; idx += 256) {
            int j = idx >> 6, d = idx & 63, p = d >> 1;
            int l = (j < 8) ? 0 : (j >> 3);
            int h = j & 7;
            float fr = frs[l][p][0], fi = frs[l][p][1];
            float w2r = attn2[m*HD + h*DD + 2*p];
            float w2i = attn2[m*HD + h*DD + 2*p + 1];
            float u = (d & 1) ? (fr*w2i - fi*w2r) : (fr*w2r + fi*w2i);
            float val = 0.25f * u + ((j < 8) ? attn1_w[m*HD + h*DD + d] : 0.f);
            Wu[(m*32 + j)*64 + d] = val;
        }
    } else if (b < FCVT_B + CW1_B + UGEN_B + HIST_B) {
        int idx = b - (FCVT_B + CW1_B + UGEN_B);
        int m = idx / HISTG;
        int e = (idx - m*HISTG)*256 + t;
        if (e < EE) {
            int dst = inst[((size_t)m*EE + e)*LL];
            atomicAdd(&cnt[m*NN + dst], 1);
        }
    } else {
        for (int i = t; i < WSUM_SZ; i += 256) wsum[i] = 0.f;
    }
}

// ---------- merged mid: gt (f16 output) | scan_partial ----------
__global__ __launch_bounds__(256) void mid_kernel(
    const float* __restrict__ features,
    const float* __restrict__ Wu,
    ushort* __restrict__ gt16,
    const int* __restrict__ cnt,
    int* __restrict__ part, int* __restrict__ bsum)
{
    __shared__ float xs[GT_TILE*65];
    __shared__ int sd[256];
    const int b = blockIdx.x;
    const int t = threadIdx.x;
    if (b < GT_B) {
        const int m = b / 224;
        const int node0 = (b - m*224) * GT_TILE;
        #pragma unroll
        for (int i = 0; i < 14; ++i) {
            int idx = t + 256*i;            // 3584 float4 = 224 rows x 16
            int r = idx >> 4, c4 = idx & 15;
            int gr = node0 + r;
            float4 v = make_float4(0.f,0.f,0.f,0.f);
            if (gr < NN) v = ((const float4*)features)[gr*16 + c4];
            float* dst = &xs[r*65 + c4*4];
            dst[0]=v.x; dst[1]=v.y; dst[2]=v.z; dst[3]=v.w;
        }
        __syncthreads();
        if (t >= GT_TILE) return;
        int node = node0 + t;
        float acc[32];
        #pragma unroll
        for (int j=0;j<32;++j) acc[j]=0.f;
        const float* Wm = Wu + m*2048;
        for (int d = 0; d < 64; ++d) {
            float x = xs[t*65 + d];
            #pragma unroll
            for (int j = 0; j < 32; ++j)
                acc[j] += x * Wm[j*64 + d];
        }
        if (node < NN) {
            ushort* o = gt16 + ((size_t)m*NN + node)*32;
            #pragma unroll
            for (int j4 = 0; j4 < 8; ++j4) {
                uint2 p;
                p.x = pk_h2(acc[j4*4+0], acc[j4*4+1]);
                p.y = pk_h2(acc[j4*4+2], acc[j4*4+3]);
                ((uint2*)o)[j4] = p;
            }
        }
    } else {
        const int bb = b - GT_B;
        const int base = bb*1024 + t*4;
        int v0=0,v1=0,v2=0,v3=0;
        if (base+3 < BINS) {
            int4 v = *(const int4*)&cnt[base];
            v0=v.x; v1=v.y; v2=v.z; v3=v.w;
        } else {
            if (base+0 < BINS) v0 = cnt[base+0];
            if (base+1 < BINS) v1 = cnt[base+1];
            if (base+2 < BINS) v2 = cnt[base+2];
            if (base+3 < BINS) v3 = cnt[base+3];
        }
        int tot = v0+v1+v2+v3;
        sd[t] = tot; __syncthreads();
        #pragma unroll
        for (int off = 1; off < 256; off <<= 1) {
            int val = (t >= off) ? sd[t-off] : 0;
            __syncthreads();
            sd[t] += val;
            __syncthreads();
        }
        int excl = sd[t] - tot;
        if (base+0 < BINS) part[base+0] = excl;
        if (base+1 < BINS) part[base+1] = excl + v0;
        if (base+2 < BINS) part[base+2] = excl + v0 + v1;
        if (base+3 < BINS) part[base+3] = excl + v0 + v1 + v2;
        if (t == 255) bsum[bb] = sd[255];
    }
}

__global__ __launch_bounds__(256) void scan_tops_kernel(
    const int* __restrict__ bsum, int* __restrict__ btop)
{
    __shared__ int sd[256];
    const int t = threadIdx.x;
    int v = (t < NBLK) ? bsum[t] : 0;
    sd[t] = v; __syncthreads();
    #pragma unroll
    for (int off = 1; off < 256; off <<= 1) {
        int val = (t >= off) ? sd[t-off] : 0;
        __syncthreads();
        sd[t] += val;
        __syncthreads();
    }
    if (t < NBLK) btop[t] = sd[t] - v;
}

// ---------- merged scat: scatter (+first-2-record embed) | seg8-build ----------
__global__ __launch_bounds__(256) void scat_kernel(
    const int4* __restrict__ inst4, const int* __restrict__ part,
    const int* __restrict__ btop, int* __restrict__ cursor,
    int4* __restrict__ rec, const int* __restrict__ cnt,
    int* __restrict__ seg8)
{
    const int b = blockIdx.x;
    const int t = threadIdx.x;
    if (b < SCAT_B) {
        int m = b / HISTG;
        int e = (b - m*HISTG)*256 + t;
        if (e >= EE) return;
        int4 v = inst4[(size_t)m*EE + e];
        int bin = m*NN + v.x;
        int c = atomicAdd(&cursor[bin], 1);
        int pos = part[bin] + btop[bin >> 10] + c;
        rec[pos] = make_int4(v.y, v.z, v.w, 0);
        if (c < 2) {
            int* s = seg8 + bin*8 + 2 + c*3;   // slots 2..4 (c==0), 5..7 (c==1)
            s[0] = v.y; s[1] = v.z; s[2] = v.w;
        }
    } else {
        int i = (b - SCAT_B)*256 + t;
        if (i < BINS)
            ((int2*)seg8)[i*4] = make_int2(part[i] + btop[i >> 10], cnt[i]);
    }
}

// ---------- fused per-node aggregation (packed f16, embedded records) ----------
// One wave per (node, m); 2 waves per block. Lane hl owns complex pair
// d=2hl,2hl+1 as half2; rotation via v_pk_fma_f16 with op_sel (free half-swap).
// gt table in f16: one gt row = 64 B = single cacheline per logit gather.
// rec4 for the ecnt>2 tail prefetched BEFORE the embedded edge-0 compute so
// its latency hides under edge-0's gathers. Setup loads (frs/x0/c0) hoisted
// above the early-exit so they overlap the seg8 round-trip.
// Plain (cached) loads/stores throughout (r8 lesson: nt hints evict and regress).
// All divergent-index cross-lane reads use __shfl (never readlane).
__global__ __launch_bounds__(128) void node_kernel(
    const unsigned int* __restrict__ f16u,
    const unsigned int* __restrict__ frs_h,
    const int4*  __restrict__ rec4,
    const int*   __restrict__ seg8,
    const ushort* __restrict__ gt16,
    ushort* __restrict__ Zb)
{
    const int m = blockIdx.y;
    const int t = threadIdx.x;
    const int lane = t & 63;
    const int hl   = lane & 31;
    const int half = lane >> 5;
    const int wid  = t >> 6;
    const int node = blockIdx.x*2 + wid;     // grid.x = NN/2 exact

    const int bin = m*NN + node;
    ushort* zrow = Zb + ((size_t)node*MM + m)*HD;
    const int4 sa = ((const int4*)seg8)[bin*2 + 0];  // {start, ecnt, a1, a2}
    const int4 sb = ((const int4*)seg8)[bin*2 + 1];  // {a3, b1, b2, b3}

    // setup loads issued early (independent of seg8)
    const uint4* fh = (const uint4*)frs_h + ((size_t)(m*32 + hl))*2;
    const uint4 ca = fh[0], cb = fh[1];
    const unsigned int ux0 = f16u[(size_t)node*32 + hl];
    const float c0 = __half2float(((const __half*)gt16)[(size_t)bin*32 + (hl & 7)]);

    const int start = __builtin_amdgcn_readfirstlane(sa.x);
    const int ecnt  = __builtin_amdgcn_readfirstlane(sa.y);
    if (ecnt == 0) {
        ((uint4*)zrow)[lane] = make_uint4(0u,0u,0u,0u);
        return;
    }

    // prefetch first tail record (overlaps edge-0 compute below)
    int4 rpre = make_int4(0,0,0,0);
    if (ecnt > 2) {
        int myq = 2 + half;
        int qq = (myq < ecnt) ? myq : (ecnt - 1);
        rpre = rec4[start + qq];
    }

    // dst feature contribution (l=0), 0.25 pre-folded
    unsigned int me0u = h2u(__hmul2(u2h(ux0), u2h(ca.x)));
    me0u = pk_fma_swap0(ux0, ca.y, me0u);

    const int lsel = hl >> 3;                // 1..3 valid for hl 8..31
    const bool gm = (hl >= 8);
    const __half* gtmh = (const __half*)gt16 + (size_t)m*NN*32;

    unsigned int acc[HH];
    #pragma unroll
    for (int h = 0; h < HH; ++h) acc[h] = 0u;
    float den = 0.f;

    auto edge = [&](int i1, int i2, int i3, bool valid) {
        int idxg = (lsel == 1) ? i1 : ((lsel == 2) ? i2 : i3);
        float gv = 0.f;
        if (gm) gv = __half2float(gtmh[(size_t)idxg*32 + hl]);
        unsigned int u1 = f16u[(size_t)i1*32 + hl];
        unsigned int u2 = f16u[(size_t)i2*32 + hl];
        unsigned int u3 = f16u[(size_t)i3*32 + hl];
        gv += __shfl_xor(gv, 16);
        gv += __shfl_xor(gv, 8);             // every lane: head (hl&7) sum l=1..3
        unsigned int me = me0u;
        me = pk_fma(u1, ca.z, me);
        me = pk_fma_swap0(u1, ca.w, me);
        me = pk_fma(u2, cb.x, me);
        me = pk_fma_swap0(u2, cb.y, me);
        me = pk_fma(u3, cb.z, me);
        me = pk_fma_swap0(u3, cb.w, me);
        float a = c0 + gv;                   // full logit for head hl&7
        a = fmaxf(a, LRELU_ALPHA*a);         // leaky-relu
        float ex = valid ? __expf(a) : 0.f;
        den += ex;                           // per-lane den for head hl&7
        float exn = __shfl_xor(ex, 1);
        unsigned int ex2 = pk_h2(ex, exn);   // even lanes 2j: [e_2j, e_2j+1]
        #pragma unroll
        for (int j = 0; j < 4; ++j) {
            unsigned int eu = __shfl(ex2, (lane & 32) + 2*j);
            acc[2*j]   = pk_fma_bcast0  (eu, me, acc[2*j]);
            acc[2*j+1] = pk_fma_bcast0hi(eu, me, acc[2*j+1]);
        }
    };

    // iteration 0 from embedded records (no rec4 dependency)
    {
        bool useB = (half == 1) && (ecnt >= 2);
        int i1 = useB ? sb.y : sa.z;
        int i2 = useB ? sb.z : sa.w;
        int i3 = useB ? sb.w : sb.x;
        edge(i1, i2, i3, half == 0 || ecnt >= 2);
    }
    if (ecnt > 2) {
        // q=2 uses the prefetched record
        edge(rpre.x, rpre.y, rpre.z, (2 + half) < ecnt);
        for (int q = 4; q < ecnt; q += 2) {
            int myq = q + half;
            bool valid = (myq < ecnt);
            int qq = valid ? myq : (ecnt - 1);
            int4 r = rec4[start + qq];
            edge(r.x, r.y, r.z, valid);
        }
    }

    // combine the two halves
    #pragma unroll
    for (int h = 0; h < HH; ++h) {
        unsigned int au = __shfl_xor(acc[h], 32);
        acc[h] = h2u(__hadd2(u2h(acc[h]), u2h(au)));
    }
    den += __shfl_xor(den, 32);

    // epilogue: each half writes 4 heads (static acc indices + 1 select)
    const int hbase = half ? 4 : 0;
    #pragma unroll
    for (int hh = 0; hh < 4; ++hh) {
        int h = hbase + hh;
        unsigned int sel = half ? acc[hh+4] : acc[hh];
        float dh = __shfl(den, h);
        float inv = __builtin_amdgcn_rcpf(dh);
        float2 v = __half22float2(u2h(sel));
        float vr = elu_f(v.x * inv);
        float vi = elu_f(v.y * inv);
        ((unsigned int*)zrow)[h*32 + hl] = pk_bf16x2(vr, vi);
    }
}

// ---------- w projection (MFMA bf16 GEMM + fused tanh/w2 epilogue) ----------

__global__ __launch_bounds__(256,3) void wproj_kernel(
    const ushort* __restrict__ Zb,
    const ushort* __restrict__ w1bf,
    const float* __restrict__ b1,
    const float* __restrict__ w2,
    float* __restrict__ wsum)
{
    __shared__ ushort As[128*72];
    __shared__ ushort Bs[128*72];
    __shared__ float wacc[MM];
    const int t = threadIdx.x;
    const int row0 = blockIdx.x * 128;
    if (t < MM) wacc[t] = 0.f;
    const int lane = t & 63;
    const int wid  = t >> 6;
    const int ln   = lane & 15;
    const int quad = lane >> 4;
    const int wr   = wid >> 1;
    const int wc   = wid & 1;

    v4f acc[4][4];
    #pragma unroll
    for (int i=0;i<4;++i)
        #pragma unroll
        for (int j=0;j<4;++j)
            acc[i][j] = (v4f){0.f,0.f,0.f,0.f};

    const uint4* zb4 = (const uint4*)Zb;     // 8 bf16 per uint4; row = 64 uint4
    const uint4* wb4 = (const uint4*)w1bf;

    for (int kt = 0; kt < 8; ++kt) {
        __syncthreads();
        #pragma unroll
        for (int i = 0; i < 4; ++i) {
            int idx = t + 256*i;            // 1024 uint4 = 128 rows x 8
            int r = idx >> 3, k8 = idx & 7;
            int gr = row0 + r;
            uint4 v = make_uint4(0u,0u,0u,0u);
            if (gr < NROWS) v = zb4[(size_t)gr*64 + kt*8 + k8];
            *(uint4*)&As[r*72 + k8*8] = v;
        }
        #pragma unroll
        for (int i = 0; i < 4; ++i) {
            int idx = t + 256*i;
            int f = idx >> 3, k8 = idx & 7;
            uint4 v = wb4[f*64 + kt*8 + k8];
            *(uint4*)&Bs[f*72 + k8*8] = v;
        }
        __syncthreads();
        #pragma unroll
        for (int kk = 0; kk < 2; ++kk) {
            v8s a[4], b[4];
            #pragma unroll
            for (int i=0;i<4;++i)
                a[i] = *(const v8s*)&As[(wr*64 + i*16 + ln)*72 + kk*32 + quad*8];
            #pragma unroll
            for (int j=0;j<4;++j)
                b[j] = *(const v8s*)&Bs[(wc*64 + j*16 + ln)*72 + kk*32 + quad*8];
            #pragma unroll
            for (int i=0;i<4;++i)
                #pragma unroll
                for (int j=0;j<4;++j)
                    acc[i][j] = __builtin_amdgcn_mfma_f32_16x16x32_bf16(
                        a[i], b[j], acc[i][j], 0, 0, 0);
        }
    }

    float b1v[4], w2v[4];
    #pragma unroll
    for (int j=0;j<4;++j) {
        int col = wc*64 + j*16 + ln;
        b1v[j] = b1[col];
        w2v[j] = w2[col];
    }
    #pragma unroll
    for (int i=0;i<4;++i) {
        #pragma unroll
        for (int reg=0;reg<4;++reg) {
            float s = 0.f;
            #pragma unroll
            for (int j=0;j<4;++j)
                s += tanh_fast(acc[i][j][reg] + b1v[j]) * w2v[j];
            s += __shfl_xor(s, 1);
            s += __shfl_xor(s, 2);
            s += __shfl_xor(s, 4);
            s += __shfl_xor(s, 8);
            int grow = row0 + wr*64 + i*16 + quad*4 + reg;
            if (ln == 0 && grow < NROWS)
                atomicAdd(&wacc[grow % MM], s);
        }
    }
    __syncthreads();
    if (t < MM)
        atomicAdd(&wsum[t*WSUM_BINS + (blockIdx.x & (WSUM_BINS-1))], wacc[t]);
}

__global__ void beta_kernel(const float* __restrict__ wsum, float* __restrict__ beta)
{
    __shared__ float sm[MM];
    int t = threadIdx.x;
    if (t < MM) {
        float s = 0.f;
        for (int i = 0; i < WSUM_BINS; ++i) s += wsum[t*WSUM_BINS + i];
        sm[t] = s / (float)NN;
    }
    __syncthreads();
    if (t < MM) {
        float a = sm[0], b = sm[1], c = sm[2];
        float mx = fmaxf(a, fmaxf(b, c));
        float e0 = __expf(a-mx), e1 = __expf(b-mx), e2 = __expf(c-mx);
        float tot = e0+e1+e2;
        float mine = (t==0?e0:(t==1?e1:e2));
        beta[t] = mine/tot;
    }
}

__global__ __launch_bounds__(256) void out_kernel(
    const ushort* __restrict__ Zb, const float* __restrict__ beta,
    float* __restrict__ out)
{
    int i = blockIdx.x*256 + threadIdx.x;    // NN*64 threads, 8 outputs each
    int n  = i >> 6;
    int jj = i & 63;
    float b0 = beta[0], b1v = beta[1], b2 = beta[2];
    const uint4* zb4 = (const uint4*)Zb;
    uint4 v0 = zb4[((size_t)n*MM + 0)*64 + jj];
    uint4 v1 = zb4[((size_t)n*MM + 1)*64 + jj];
    uint4 v2 = zb4[((size_t)n*MM + 2)*64 + jj];
    float o[8];
    o[0] = b0*bf_lo(v0.x) + b1v*bf_lo(v1.x) + b2*bf_lo(v2.x);
    o[1] = b0*bf_hi(v0.x) + b1v*bf_hi(v1.x) + b2*bf_hi(v2.x);
    o[2] = b0*bf_lo(v0.y) + b1v*bf_lo(v1.y) + b2*bf_lo(v2.y);
    o[3] = b0*bf_hi(v0.y) + b1v*bf_hi(v1.y) + b2*bf_hi(v2.y);
    o[4] = b0*bf_lo(v0.z) + b1v*bf_lo(v1.z) + b2*bf_lo(v2.z);
    o[5] = b0*bf_hi(v0.z) + b1v*bf_hi(v1.z) + b2*bf_hi(v2.z);
    o[6] = b0*bf_lo(v0.w) + b1v*bf_lo(v1.w) + b2*bf_lo(v2.w);
    o[7] = b0*bf_hi(v0.w) + b1v*bf_hi(v1.w) + b2*bf_hi(v2.w);
    float4* op = (float4*)(out + (size_t)n*HD + jj*8);
    op[0] = make_float4(o[0],o[1],o[2],o[3]);
    op[1] = make_float4(o[4],o[5],o[6],o[7]);
}

extern "C" void kernel_launch(void* const* d_in, const int* in_sizes, int n_in,
                              void* d_out, int out_size, void* d_ws, size_t ws_size,
                              hipStream_t stream) {
    const float* features = (const float*)d_in[0];
    const float* attn1_w  = (const float*)d_in[1];
    const float* attn2    = (const float*)d_in[2];
    const float* r_vec    = (const float*)d_in[3];
    const float* proj_w1  = (const float*)d_in[4];
    const float* proj_b1  = (const float*)d_in[5];
    const float* proj_w2  = (const float*)d_in[6];
    const int*   inst     = (const int*)d_in[7];
    const int*   etypes   = (const int*)d_in[8];
    float* out = (float*)d_out;

    float* ws    = (float*)d_ws;
    ushort* Zb   = (ushort*)(ws + OFF_ZB);
    float* wsum  = ws + OFF_WSUM;
    float* beta  = ws + OFF_BETA;
    ushort* w1bf = (ushort*)(ws + OFF_W1BF);
    float* Wu    = ws + OFF_WU;
    unsigned int* frs_h = (unsigned int*)(ws + OFF_FRS);
    ushort* gt16 = (ushort*)(ws + OFF_GT);
    int* ints    = (int*)(ws + OFF_INTS);
    int* cnt     = ints + IOFF_CNT;
    int* cursor  = ints + IOFF_CURSOR;
    int* part    = ints + IOFF_PART;
    int* bsum    = ints + IOFF_BSUM;
    int* btop    = ints + IOFF_BTOP;
    int* seg8    = ints + IOFF_SEG8;
    int4* rec4   = (int4*)(ints + IOFF_REC);
    ushort* f16  = (ushort*)(ws + OFF_F16);

    hipMemsetAsync(cnt, 0, (size_t)2*BINS*sizeof(int), stream);

    prep_kernel<<<PREP_B, 256, 0, stream>>>(
        features, f16, proj_w1, w1bf, r_vec, etypes, attn1_w, attn2,
        Wu, frs_h, inst, cnt, wsum);
    mid_kernel<<<MID_B, 256, 0, stream>>>(features, Wu, gt16, cnt, part, bsum);
    scan_tops_kernel<<<1, 256, 0, stream>>>(bsum, btop);
    scat_kernel<<<SCT_B, 256, 0, stream>>>(
        (const int4*)inst, part, btop, cursor, rec4, cnt, seg8);
    node_kernel<<<dim3(NN/2, MM), 128, 0, stream>>>(
        (const unsigned int*)f16, frs_h, rec4, seg8, gt16, Zb);
    wproj_kernel<<<(NROWS + 127)/128, 256, 0, stream>>>(Zb, w1bf, proj_b1, proj_w2, wsum);
    beta_kernel<<<1, 64, 0, stream>>>(wsum, beta);
    out_kernel<<<NN*64/256, 256, 0, stream>>>(Zb, beta, out);
}

// Round 12
// 344.603 us; speedup vs baseline: 1.0248x; 1.0248x over previous
//
#include <hip/hip_runtime.h>
#include <hip/hip_bf16.h>
#include <hip/hip_fp16.h>
#include <math.h>

#define NN 50000
#define DD 64
#define MM 3
#define EE 100000
#define LL 4
#define HH 8
#define FHH 128
#define HD 512
#define NROWS (NN*MM)
#define LRELU_ALPHA 0.01f

#define WSUM_BINS 256
#define WSUM_SZ (MM*WSUM_BINS)
#define BINS (MM*NN)               /* 150,000 */
#define NBLK ((BINS + 1023)/1024)  /* 147 */
#define GT_TILE 224

/* prep_kernel block ranges */
#define FCVT_B 3125                /* NN*DD/4/256 */
#define CW1_B  64                  /* 16384 float4 / 256 */
#define UGEN_B 3
#define HISTG  392                 /* (EE+255)/256 */
#define HIST_B (HISTG*MM)
#define PREP_B (FCVT_B + CW1_B + UGEN_B + HIST_B + 1)

/* mid_kernel block ranges */
#define GT_B   (224*MM)            /* ceil(NN/GT_TILE)*MM = 672 */
#define MID_B  (GT_B + NBLK)

/* scat_kernel block ranges */
#define SCAT_B (HISTG*MM)          /* 1176 */
#define SEGC_B ((BINS + 255)/256)  /* 587 */
#define SCT_B  (SCAT_B + SEGC_B)

/* workspace layout (float offsets), all 16B aligned */
#define OFF_ZB    0                          /* bf16[NROWS*512] = 38.4M floats */
#define OFF_WSUM  (NROWS*HD/2)               /* 38,400,000 */
#define OFF_BETA  (OFF_WSUM + WSUM_SZ)
#define OFF_W1BF  (OFF_BETA + 16)
#define OFF_WU    (OFF_W1BF + 32768)         /* 3*32*64 = 6144 floats */
#define OFF_FRS   (OFF_WU + 6144)            /* 3*32*8 u32 = 768 */
#define OFF_GT    (OFF_FRS + 768)            /* f16[3*50000*32] = 2.4M floats used */
#define OFF_INTS  (OFF_GT + MM*NN*32)
#define IOFF_CNT    0
#define IOFF_CURSOR (IOFF_CNT + BINS)
#define IOFF_PART   (IOFF_CURSOR + BINS)
#define IOFF_BSUM   (IOFF_PART + BINS)
#define IOFF_BTOP   (IOFF_BSUM + 256)
#define IOFF_SEG8   (IOFF_BTOP + 256)        /* int[8*BINS] = 1.2M ints */
#define IOFF_REC    (IOFF_SEG8 + 8*BINS)     /* int4[MM*EE] = 1.2M ints */
#define INTS_END    (IOFF_REC + 4*MM*EE)
#define OFF_F16   (OFF_INTS + INTS_END)      /* f16[NN*DD] = 1.6M floats */

typedef short v8s __attribute__((ext_vector_type(8)));
typedef float v4f __attribute__((ext_vector_type(4)));

__device__ __forceinline__ float elu_f(float x) {
    return x > 0.f ? x : (__expf(x) - 1.f);
}

__device__ __forceinline__ float tanh_fast(float x) {
    float e = __expf(2.f * x);
    return 1.f - 2.f / (e + 1.f);
}

__device__ __forceinline__ unsigned int pk_bf16x2(float x, float y) {
    float2 f2; f2.x = x; f2.y = y;
    __hip_bfloat162 h = __float22bfloat162_rn(f2);
    union { __hip_bfloat162 h; unsigned int u; } cv;
    cv.h = h;
    return cv.u;
}

__device__ __forceinline__ unsigned int pk_h2(float x, float y) {
    __half2 h = __floats2half2_rn(x, y);
    union { __half2 h; unsigned int u; } cv;
    cv.h = h;
    return cv.u;
}

__device__ __forceinline__ float bf_lo(unsigned int u) {
    union { unsigned int x; float f; } c; c.x = u << 16; return c.f;
}
__device__ __forceinline__ float bf_hi(unsigned int u) {
    union { unsigned int x; float f; } c; c.x = u & 0xffff0000u; return c.f;
}

__device__ __forceinline__ __half2 u2h(unsigned int u) {
    union { unsigned int x; __half2 h; } c; c.x = u; return c.h;
}
__device__ __forceinline__ unsigned int h2u(__half2 h) {
    union { __half2 h; unsigned int x; } c; c.h = h; return c.x;
}

/* v_pk_fma_f16: d = s0*s1 + s2 (packed) */
__device__ __forceinline__ unsigned int pk_fma(unsigned int x, unsigned int c, unsigned int a) {
    unsigned int d;
    asm("v_pk_fma_f16 %0, %1, %2, %3"
        : "=v"(d) : "v"(x), "v"(c), "v"(a));
    return d;
}
/* same, src0 halves swapped (free via op_sel) */
__device__ __forceinline__ unsigned int pk_fma_swap0(unsigned int x, unsigned int c, unsigned int a) {
    unsigned int d;
    asm("v_pk_fma_f16 %0, %1, %2, %3 op_sel:[1,0,0] op_sel_hi:[0,1,1]"
        : "=v"(d) : "v"(x), "v"(c), "v"(a));
    return d;
}
/* same, src0 LOW half broadcast to both lanes */
__device__ __forceinline__ unsigned int pk_fma_bcast0(unsigned int x, unsigned int c, unsigned int a) {
    unsigned int d;
    asm("v_pk_fma_f16 %0, %1, %2, %3 op_sel:[0,0,0] op_sel_hi:[0,1,1]"
        : "=v"(d) : "v"(x), "v"(c), "v"(a));
    return d;
}
/* same, src0 HIGH half broadcast to both lanes */
__device__ __forceinline__ unsigned int pk_fma_bcast0hi(unsigned int x, unsigned int c, unsigned int a) {
    unsigned int d;
    asm("v_pk_fma_f16 %0, %1, %2, %3 op_sel:[1,0,0] op_sel_hi:[1,1,1]"
        : "=v"(d) : "v"(x), "v"(c), "v"(a));
    return d;
}

// compute frs chain for module m into LDS (threads 0..31)
__device__ __forceinline__ void build_frs(
    float frs[LL][DD/2][2], const float* r_vec, const int* etypes, int m, int t)
{
    if (t < DD/2) {
        float cr = 1.f, ci = 0.f;
        frs[LL-1][t][0] = 1.f; frs[LL-1][t][1] = 0.f;
        for (int i = LL-2; i >= 0; --i) {
            int et = etypes[m*(LL-1) + i];
            float rr = r_vec[((et>>1)*(DD/2) + t)*2 + 0];
            float ri = r_vec[((et>>1)*(DD/2) + t)*2 + 1];
            float inv = rsqrtf(rr*rr + ri*ri);
            rr *= inv; ri *= inv;
            if (et & 1) ri = -ri;
            float nr = cr*rr - ci*ri;
            float ni = cr*ri + ci*rr;
            cr = nr; ci = ni;
            frs[i][t][0] = cr; frs[i][t][1] = ci;
        }
    }
}

// ---------- merged prep: fcvt | cvt_w1 | ugen | hist | wsum-zero ----------
__global__ __launch_bounds__(256) void prep_kernel(
    const float* __restrict__ features, ushort* __restrict__ f16,
    const float* __restrict__ w1, ushort* __restrict__ w1bf,
    const float* __restrict__ r_vec, const int* __restrict__ etypes,
    const float* __restrict__ attn1_w, const float* __restrict__ attn2,
    float* __restrict__ Wu, unsigned int* __restrict__ frs_h,
    const int* __restrict__ inst, int* __restrict__ cnt,
    float* __restrict__ wsum)
{
    const int b = blockIdx.x;
    const int t = threadIdx.x;
    if (b < FCVT_B) {
        int i = b*256 + t;
        float4 v = ((const float4*)features)[i];
        ((uint2*)f16)[i] = make_uint2(pk_h2(v.x, v.y), pk_h2(v.z, v.w));
    } else if (b < FCVT_B + CW1_B) {
        int i = (b - FCVT_B)*256 + t;
        float4 v = ((const float4*)w1)[i];
        uint2 p; p.x = pk_bf16x2(v.x, v.y); p.y = pk_bf16x2(v.z, v.w);
        ((uint2*)w1bf)[i] = p;
    } else if (b < FCVT_B + CW1_B + UGEN_B) {
        const int m = b - (FCVT_B + CW1_B);
        __shared__ float frs[LL][DD/2][2];
        build_frs(frs, r_vec, etypes, m, t);
        __syncthreads();
        if (t < 32) {
            // packed half2 rotation consts, 0.25 folded:
            // [rr0, ii0, rr1, ii1], [rr2, ii2, rr3, ii3]
            unsigned int vals[8];
            #pragma unroll
            for (int l = 0; l < LL; ++l) {
                float fr = 0.25f * frs[l][t][0];
                float fi = 0.25f * frs[l][t][1];
                vals[2*l+0] = pk_h2(fr, fr);
                vals[2*l+1] = pk_h2(-fi, fi);
            }
            uint4* dst = (uint4*)frs_h + (m*32 + t)*2;
            dst[0] = make_uint4(vals[0], vals[1], vals[2], vals[3]);
            dst[1] = make_uint4(vals[4], vals[5], vals[6], vals[7]);
        }
        for (int idx = t; idx < 32*64; idx += 256) {
            int j = idx >> 6, d = idx & 63, p = d >> 1;
            int l = (j < 8) ? 0 : (j >> 3);
            int h = j & 7;
            float fr = frs[l][p][0], fi = frs[l][p][1];
            float w2r = attn2[m*HD + h*DD + 2*p];
            float w2i = attn2[m*HD + h*DD + 2*p + 1];
            float u = (d & 1) ? (fr*w2i - fi*w2r) : (fr*w2r + fi*w2i);
            float val = 0.25f * u + ((j < 8) ? attn1_w[m*HD + h*DD + d] : 0.f);
            Wu[(m*32 + j)*64 + d] = val;
        }
    } else if (b < FCVT_B + CW1_B + UGEN_B + HIST_B) {
        int idx = b - (FCVT_B + CW1_B + UGEN_B);
        int m = idx / HISTG;
        int e = (idx - m*HISTG)*256 + t;
        if (e < EE) {
            int dst = inst[((size_t)m*EE + e)*LL];
            atomicAdd(&cnt[m*NN + dst], 1);
        }
    } else {
        for (int i = t; i < WSUM_SZ; i += 256) wsum[i] = 0.f;
    }
}

// ---------- merged mid: gt (f16 output) | scan_partial ----------
__global__ __launch_bounds__(256) void mid_kernel(
    const float* __restrict__ features,
    const float* __restrict__ Wu,
    ushort* __restrict__ gt16,
    const int* __restrict__ cnt,
    int* __restrict__ part, int* __restrict__ bsum)
{
    __shared__ float xs[GT_TILE*65];
    __shared__ int sd[256];
    const int b = blockIdx.x;
    const int t = threadIdx.x;
    if (b < GT_B) {
        const int m = b / 224;
        const int node0 = (b - m*224) * GT_TILE;
        #pragma unroll
        for (int i = 0; i < 14; ++i) {
            int idx = t + 256*i;            // 3584 float4 = 224 rows x 16
            int r = idx >> 4, c4 = idx & 15;
            int gr = node0 + r;
            float4 v = make_float4(0.f,0.f,0.f,0.f);
            if (gr < NN) v = ((const float4*)features)[gr*16 + c4];
            float* dst = &xs[r*65 + c4*4];
            dst[0]=v.x; dst[1]=v.y; dst[2]=v.z; dst[3]=v.w;
        }
        __syncthreads();
        if (t >= GT_TILE) return;
        int node = node0 + t;
        float acc[32];
        #pragma unroll
        for (int j=0;j<32;++j) acc[j]=0.f;
        const float* Wm = Wu + m*2048;
        for (int d = 0; d < 64; ++d) {
            float x = xs[t*65 + d];
            #pragma unroll
            for (int j = 0; j < 32; ++j)
                acc[j] += x * Wm[j*64 + d];
        }
        if (node < NN) {
            ushort* o = gt16 + ((size_t)m*NN + node)*32;
            #pragma unroll
            for (int j4 = 0; j4 < 8; ++j4) {
                uint2 p;
                p.x = pk_h2(acc[j4*4+0], acc[j4*4+1]);
                p.y = pk_h2(acc[j4*4+2], acc[j4*4+3]);
                ((uint2*)o)[j4] = p;
            }
        }
    } else {
        const int bb = b - GT_B;
        const int base = bb*1024 + t*4;
        int v0=0,v1=0,v2=0,v3=0;
        if (base+3 < BINS) {
            int4 v = *(const int4*)&cnt[base];
            v0=v.x; v1=v.y; v2=v.z; v3=v.w;
        } else {
            if (base+0 < BINS) v0 = cnt[base+0];
            if (base+1 < BINS) v1 = cnt[base+1];
            if (base+2 < BINS) v2 = cnt[base+2];
            if (base+3 < BINS) v3 = cnt[base+3];
        }
        int tot = v0+v1+v2+v3;
        sd[t] = tot; __syncthreads();
        #pragma unroll
        for (int off = 1; off < 256; off <<= 1) {
            int val = (t >= off) ? sd[t-off] : 0;
            __syncthreads();
            sd[t] += val;
            __syncthreads();
        }
        int excl = sd[t] - tot;
        if (base+0 < BINS) part[base+0] = excl;
        if (base+1 < BINS) part[base+1] = excl + v0;
        if (base+2 < BINS) part[base+2] = excl + v0 + v1;
        if (base+3 < BINS) part[base+3] = excl + v0 + v1 + v2;
        if (t == 255) bsum[bb] = sd[255];
    }
}

__global__ __launch_bounds__(256) void scan_tops_kernel(
    const int* __restrict__ bsum, int* __restrict__ btop)
{
    __shared__ int sd[256];
    const int t = threadIdx.x;
    int v = (t < NBLK) ? bsum[t] : 0;
    sd[t] = v; __syncthreads();
    #pragma unroll
    for (int off = 1; off < 256; off <<= 1) {
        int val = (t >= off) ? sd[t-off] : 0;
        __syncthreads();
        sd[t] += val;
        __syncthreads();
    }
    if (t < NBLK) btop[t] = sd[t] - v;
}

// ---------- merged scat: scatter (+first-2-record embed) | seg8-build ----------
__global__ __launch_bounds__(256) void scat_kernel(
    const int4* __restrict__ inst4, const int* __restrict__ part,
    const int* __restrict__ btop, int* __restrict__ cursor,
    int4* __restrict__ rec, const int* __restrict__ cnt,
    int* __restrict__ seg8)
{
    const int b = blockIdx.x;
    const int t = threadIdx.x;
    if (b < SCAT_B) {
        int m = b / HISTG;
        int e = (b - m*HISTG)*256 + t;
        if (e >= EE) return;
        int4 v = inst4[(size_t)m*EE + e];
        int bin = m*NN + v.x;
        int c = atomicAdd(&cursor[bin], 1);
        int pos = part[bin] + btop[bin >> 10] + c;
        rec[pos] = make_int4(v.y, v.z, v.w, 0);
        if (c < 2) {
            int* s = seg8 + bin*8 + 2 + c*3;   // slots 2..4 (c==0), 5..7 (c==1)
            s[0] = v.y; s[1] = v.z; s[2] = v.w;
        }
    } else {
        int i = (b - SCAT_B)*256 + t;
        if (i < BINS)
            ((int2*)seg8)[i*4] = make_int2(part[i] + btop[i >> 10], cnt[i]);
    }
}

// ---------- fused per-node aggregation (one node per wave-half) ----------
// 2 nodes per wave (half 0 = even node, half 1 = odd node); each half owns its
// node's edges, acc, den, and epilogue -> NO cross-half combines (epilogue
// LDS-ops 17->8 per node) and wave count halves. Lane hl owns complex pair
// d=2hl,2hl+1 as half2; rotation via v_pk_fma_f16 op_sel. Invalid-edge indices
// clamped to own node BEFORE gathers (embedded slots of empty bins are
// uninitialized). den==0 half -> inv=0 (avoids 0*inf NaN), acc=0 -> writes 0.
// Plain cached loads/stores (r8 lesson: nt hints evict warm L2/L3, regress).
// All divergent-index cross-lane reads use __shfl (never readlane).
__global__ __launch_bounds__(128) void node_kernel(
    const unsigned int* __restrict__ f16u,
    const unsigned int* __restrict__ frs_h,
    const int4*  __restrict__ rec4,
    const int*   __restrict__ seg8,
    const ushort* __restrict__ gt16,
    ushort* __restrict__ Zb)
{
    const int m = blockIdx.y;
    const int t = threadIdx.x;
    const int lane = t & 63;
    const int hl   = lane & 31;
    const int half = lane >> 5;
    const int wid  = t >> 6;
    const int node = blockIdx.x*4 + wid*2 + half;   // grid.x = NN/4 exact

    const int bin = m*NN + node;
    ushort* zrow = Zb + ((size_t)node*MM + m)*HD;
    const int4 sa = ((const int4*)seg8)[bin*2 + 0];  // {start, ecnt, a1, a2}
    const int4 sb = ((const int4*)seg8)[bin*2 + 1];  // {a3, b1, b2, b3}

    // setup loads issued early
    const uint4* fh = (const uint4*)frs_h + ((size_t)(m*32 + hl))*2;
    const uint4 ca = fh[0], cb = fh[1];
    const unsigned int ux0 = f16u[(size_t)node*32 + hl];
    const float c0 = __half2float(((const __half*)gt16)[(size_t)bin*32 + (hl & 7)]);

    const int start = sa.x;          // per-half uniform (VGPR)
    const int ecnt  = sa.y;          // per-half uniform (VGPR)
    int eo = __shfl_xor(ecnt, 32);
    int emax = __builtin_amdgcn_readfirstlane(max(ecnt, eo));  // wave-uniform
    if (emax == 0) {                 // both halves empty (~1.8%)
        ((uint4*)zrow)[hl] = make_uint4(0u,0u,0u,0u);
        ((uint4*)zrow)[hl + 32] = make_uint4(0u,0u,0u,0u);
        return;
    }

    // dst feature contribution (l=0), 0.25 pre-folded
    unsigned int me0u = h2u(__hmul2(u2h(ux0), u2h(ca.x)));
    me0u = pk_fma_swap0(ux0, ca.y, me0u);

    const int lsel = hl >> 3;                // 1..3 valid for hl 8..31
    const bool gm = (hl >= 8);
    const __half* gtmh = (const __half*)gt16 + (size_t)m*NN*32;

    unsigned int acc[HH];
    #pragma unroll
    for (int h = 0; h < HH; ++h) acc[h] = 0u;
    float den = 0.f;

    for (int q = 0; q < emax; ++q) {
        bool valid = (q < ecnt);
        int i1, i2, i3;
        if (q == 0)      { i1 = sa.z; i2 = sa.w; i3 = sb.x; }
        else if (q == 1) { i1 = sb.y; i2 = sb.z; i3 = sb.w; }
        else {
            int qq = valid ? q : (ecnt > 0 ? ecnt - 1 : 0);
            int4 r = rec4[start + qq];
            i1 = r.x; i2 = r.y; i3 = r.z;
        }
        if (!valid) { i1 = node; i2 = node; i3 = node; }  // safe indices, masked by ex=0

        int idxg = (lsel == 1) ? i1 : ((lsel == 2) ? i2 : i3);
        float gv = 0.f;
        if (gm) gv = __half2float(gtmh[(size_t)idxg*32 + hl]);
        unsigned int u1 = f16u[(size_t)i1*32 + hl];
        unsigned int u2 = f16u[(size_t)i2*32 + hl];
        unsigned int u3 = f16u[(size_t)i3*32 + hl];
        gv += __shfl_xor(gv, 16);
        gv += __shfl_xor(gv, 8);             // every lane: head (hl&7) sum l=1..3
        unsigned int me = me0u;
        me = pk_fma(u1, ca.z, me);
        me = pk_fma_swap0(u1, ca.w, me);
        me = pk_fma(u2, cb.x, me);
        me = pk_fma_swap0(u2, cb.y, me);
        me = pk_fma(u3, cb.z, me);
        me = pk_fma_swap0(u3, cb.w, me);
        float a = c0 + gv;                   // full logit for head hl&7
        a = fmaxf(a, LRELU_ALPHA*a);         // leaky-relu
        float ex = valid ? __expf(a) : 0.f;
        den += ex;                           // per-lane den for head hl&7
        float exn = __shfl_xor(ex, 1);
        unsigned int ex2 = pk_h2(ex, exn);   // even lanes 2j: [e_2j, e_2j+1]
        #pragma unroll
        for (int j = 0; j < 4; ++j) {
            unsigned int eu = __shfl(ex2, (lane & 32) + 2*j);
            acc[2*j]   = pk_fma_bcast0  (eu, me, acc[2*j]);
            acc[2*j+1] = pk_fma_bcast0hi(eu, me, acc[2*j+1]);
        }
    }

    // epilogue: each half writes ALL 8 heads of its own node (no combines)
    #pragma unroll
    for (int h = 0; h < HH; ++h) {
        float dh = __shfl(den, (lane & 32) + h);
        float inv = (dh > 0.f) ? __builtin_amdgcn_rcpf(dh) : 0.f;
        float2 v = __half22float2(u2h(acc[h]));
        float vr = elu_f(v.x * inv);
        float vi = elu_f(v.y * inv);
        ((unsigned int*)zrow)[h*32 + hl] = pk_bf16x2(vr, vi);
    }
}

// ---------- w projection (MFMA bf16 GEMM + fused tanh/w2 epilogue) ----------

__global__ __launch_bounds__(256,3) void wproj_kernel(
    const ushort* __restrict__ Zb,
    const ushort* __restrict__ w1bf,
    const float* __restrict__ b1,
    const float* __restrict__ w2,
    float* __restrict__ wsum)
{
    __shared__ ushort As[128*72];
    __shared__ ushort Bs[128*72];
    __shared__ float wacc[MM];
    const int t = threadIdx.x;
    const int row0 = blockIdx.x * 128;
    if (t < MM) wacc[t] = 0.f;
    const int lane = t & 63;
    const int wid  = t >> 6;
    const int ln   = lane & 15;
    const int quad = lane >> 4;
    const int wr   = wid >> 1;
    const int wc   = wid & 1;

    v4f acc[4][4];
    #pragma unroll
    for (int i=0;i<4;++i)
        #pragma unroll
        for (int j=0;j<4;++j)
            acc[i][j] = (v4f){0.f,0.f,0.f,0.f};

    const uint4* zb4 = (const uint4*)Zb;     // 8 bf16 per uint4; row = 64 uint4
    const uint4* wb4 = (const uint4*)w1bf;

    for (int kt = 0; kt < 8; ++kt) {
        __syncthreads();
        #pragma unroll
        for (int i = 0; i < 4; ++i) {
            int idx = t + 256*i;            // 1024 uint4 = 128 rows x 8
            int r = idx >> 3, k8 = idx & 7;
            int gr = row0 + r;
            uint4 v = make_uint4(0u,0u,0u,0u);
            if (gr < NROWS) v = zb4[(size_t)gr*64 + kt*8 + k8];
            *(uint4*)&As[r*72 + k8*8] = v;
        }
        #pragma unroll
        for (int i = 0; i < 4; ++i) {
            int idx = t + 256*i;
            int f = idx >> 3, k8 = idx & 7;
            uint4 v = wb4[f*64 + kt*8 + k8];
            *(uint4*)&Bs[f*72 + k8*8] = v;
        }
        __syncthreads();
        #pragma unroll
        for (int kk = 0; kk < 2; ++kk) {
            v8s a[4], b[4];
            #pragma unroll
            for (int i=0;i<4;++i)
                a[i] = *(const v8s*)&As[(wr*64 + i*16 + ln)*72 + kk*32 + quad*8];
            #pragma unroll
            for (int j=0;j<4;++j)
                b[j] = *(const v8s*)&Bs[(wc*64 + j*16 + ln)*72 + kk*32 + quad*8];
            #pragma unroll
            for (int i=0;i<4;++i)
                #pragma unroll
                for (int j=0;j<4;++j)
                    acc[i][j] = __builtin_amdgcn_mfma_f32_16x16x32_bf16(
                        a[i], b[j], acc[i][j], 0, 0, 0);
        }
    }

    float b1v[4], w2v[4];
    #pragma unroll
    for (int j=0;j<4;++j) {
        int col = wc*64 + j*16 + ln;
        b1v[j] = b1[col];
        w2v[j] = w2[col];
    }
    #pragma unroll
    for (int i=0;i<4;++i) {
        #pragma unroll
        for (int reg=0;reg<4;++reg) {
            float s = 0.f;
            #pragma unroll
            for (int j=0;j<4;++j)
                s += tanh_fast(acc[i][j][reg] + b1v[j]) * w2v[j];
            s += __shfl_xor(s, 1);
            s += __shfl_xor(s, 2);
            s += __shfl_xor(s, 4);
            s += __shfl_xor(s, 8);
            int grow = row0 + wr*64 + i*16 + quad*4 + reg;
            if (ln == 0 && grow < NROWS)
                atomicAdd(&wacc[grow % MM], s);
        }
    }
    __syncthreads();
    if (t < MM)
        atomicAdd(&wsum[t*WSUM_BINS + (blockIdx.x & (WSUM_BINS-1))], wacc[t]);
}

__global__ void beta_kernel(const float* __restrict__ wsum, float* __restrict__ beta)
{
    __shared__ float sm[MM];
    int t = threadIdx.x;
    if (t < MM) {
        float s = 0.f;
        for (int i = 0; i < WSUM_BINS; ++i) s += wsum[t*WSUM_BINS + i];
        sm[t] = s / (float)NN;
    }
    __syncthreads();
    if (t < MM) {
        float a = sm[0], b = sm[1], c = sm[2];
        float mx = fmaxf(a, fmaxf(b, c));
        float e0 = __expf(a-mx), e1 = __expf(b-mx), e2 = __expf(c-mx);
        float tot = e0+e1+e2;
        float mine = (t==0?e0:(t==1?e1:e2));
        beta[t] = mine/tot;
    }
}

__global__ __launch_bounds__(256) void out_kernel(
    const ushort* __restrict__ Zb, const float* __restrict__ beta,
    float* __restrict__ out)
{
    int i = blockIdx.x*256 + threadIdx.x;    // NN*64 threads, 8 outputs each
    int n  = i >> 6;
    int jj = i & 63;
    float b0 = beta[0], b1v = beta[1], b2 = beta[2];
    const uint4* zb4 = (const uint4*)Zb;
    uint4 v0 = zb4[((size_t)n*MM + 0)*64 + jj];
    uint4 v1 = zb4[((size_t)n*MM + 1)*64 + jj];
    uint4 v2 = zb4[((size_t)n*MM + 2)*64 + jj];
    float o[8];
    o[0] = b0*bf_lo(v0.x) + b1v*bf_lo(v1.x) + b2*bf_lo(v2.x);
    o[1] = b0*bf_hi(v0.x) + b1v*bf_hi(v1.x) + b2*bf_hi(v2.x);
    o[2] = b0*bf_lo(v0.y) + b1v*bf_lo(v1.y) + b2*bf_lo(v2.y);
    o[3] = b0*bf_hi(v0.y) + b1v*bf_hi(v1.y) + b2*bf_hi(v2.y);
    o[4] = b0*bf_lo(v0.z) + b1v*bf_lo(v1.z) + b2*bf_lo(v2.z);
    o[5] = b0*bf_hi(v0.z) + b1v*bf_hi(v1.z) + b2*bf_hi(v2.z);
    o[6] = b0*bf_lo(v0.w) + b1v*bf_lo(v1.w) + b2*bf_lo(v2.w);
    o[7] = b0*bf_hi(v0.w) + b1v*bf_hi(v1.w) + b2*bf_hi(v2.w);
    float4* op = (float4*)(out + (size_t)n*HD + jj*8);
    op[0] = make_float4(o[0],o[1],o[2],o[3]);
    op[1] = make_float4(o[4],o[5],o[6],o[7]);
}

extern "C" void kernel_launch(void* const* d_in, const int* in_sizes, int n_in,
                              void* d_out, int out_size, void* d_ws, size_t ws_size,
                              hipStream_t stream) {
    const float* features = (const float*)d_in[0];
    const float* attn1_w  = (const float*)d_in[1];
    const float* attn2    = (const float*)d_in[2];
    const float* r_vec    = (const float*)d_in[3];
    const float* proj_w1  = (const float*)d_in[4];
    const float* proj_b1  = (const float*)d_in[5];
    const float* proj_w2  = (const float*)d_in[6];
    const int*   inst     = (const int*)d_in[7];
    const int*   etypes   = (const int*)d_in[8];
    float* out = (float*)d_out;

    float* ws    = (float*)d_ws;
    ushort* Zb   = (ushort*)(ws + OFF_ZB);
    float* wsum  = ws + OFF_WSUM;
    float* beta  = ws + OFF_BETA;
    ushort* w1bf = (ushort*)(ws + OFF_W1BF);
    float* Wu    = ws + OFF_WU;
    unsigned int* frs_h = (unsigned int*)(ws + OFF_FRS);
    ushort* gt16 = (ushort*)(ws + OFF_GT);
    int* ints    = (int*)(ws + OFF_INTS);
    int* cnt     = ints + IOFF_CNT;
    int* cursor  = ints + IOFF_CURSOR;
    int* part    = ints + IOFF_PART;
    int* bsum    = ints + IOFF_BSUM;
    int* btop    = ints + IOFF_BTOP;
    int* seg8    = ints + IOFF_SEG8;
    int4* rec4   = (int4*)(ints + IOFF_REC);
    ushort* f16  = (ushort*)(ws + OFF_F16);

    hipMemsetAsync(cnt, 0, (size_t)2*BINS*sizeof(int), stream);

    prep_kernel<<<PREP_B, 256, 0, stream>>>(
        features, f16, proj_w1, w1bf, r_vec, etypes, attn1_w, attn2,
        Wu, frs_h, inst, cnt, wsum);
    mid_kernel<<<MID_B, 256, 0, stream>>>(features, Wu, gt16, cnt, part, bsum);
    scan_tops_kernel<<<1, 256, 0, stream>>>(bsum, btop);
    scat_kernel<<<SCT_B, 256, 0, stream>>>(
        (const int4*)inst, part, btop, cursor, rec4, cnt, seg8);
    node_kernel<<<dim3(NN/4, MM), 128, 0, stream>>>(
        (const unsigned int*)f16, frs_h, rec4, seg8, gt16, Zb);
    wproj_kernel<<<(NROWS + 127)/128, 256, 0, stream>>>(Zb, w1bf, proj_b1, proj_w2, wsum);
    beta_kernel<<<1, 64, 0, stream>>>(wsum, beta);
    out_kernel<<<NN*64/256, 256, 0, stream>>>(Zb, beta, out);
}